// Round 7
// baseline (333.809 us; speedup 1.0000x reference)
//
#include <hip/hip_runtime.h>
#include <stdint.h>

#define EMBED 768
#define HD 64
#define SEQ 4096
#define BATCH 4
#define NROW (BATCH * SEQ)   // 16384
#define MAXCH 16             // max 256-key chunks per 4096-key band
#define NDENSE 2176          // total real (band,chunk) blocks per batch*4

typedef __bf16 bf16x8 __attribute__((ext_vector_type(8)));
typedef __bf16 bf16x4 __attribute__((ext_vector_type(4)));
typedef float f32x4 __attribute__((ext_vector_type(4)));

// ---------------- W -> wT [192][768] bf16 (once, tiny) ----------------
__global__ __launch_bounds__(256)
void wconv_kernel(const float* __restrict__ Wq, const float* __restrict__ Wk,
                  const float* __restrict__ Wv, __bf16* __restrict__ wT) {
    int id = blockIdx.x * 256 + threadIdx.x;   // < 192*768
    int c = id / EMBED, k = id - c * EMBED;
    const float* W = (c < 64) ? Wq : (c < 128) ? Wk : Wv;
    wT[id] = (__bf16)W[(size_t)k * HD + (c & 63)];
}

// ---------------- fused QKV GEMM ----------------
// grid: 1024 blocks x 256 thr. Block = 16 rows x 192 cols; wave w = 48 cols
// (3 accs). All waves read the same 16 A-rows (L1-served); hidden read 1x.
// Q output is PRE-SCALED by log2(e)/sqrt(64) for the attn exp2 softmax.
__global__ __launch_bounds__(256, 4)
void qkv_gemm_kernel(const float* __restrict__ hidden, const __bf16* __restrict__ wT,
                     const float* __restrict__ bq, const float* __restrict__ bk,
                     const float* __restrict__ bv,
                     __bf16* __restrict__ qo, __bf16* __restrict__ ko,
                     __bf16* __restrict__ vto) {
    const int m0 = blockIdx.x * 16;
    const int w  = threadIdx.x >> 6;
    const int lane = threadIdx.x & 63, lr = lane & 15, lg = lane >> 4;

    f32x4 acc[3];
    #pragma unroll
    for (int j = 0; j < 3; ++j) acc[j] = (f32x4){0.f, 0.f, 0.f, 0.f};

    const float* hrow = hidden + (size_t)(m0 + lr) * EMBED + lg * 8;

    for (int k0 = 0; k0 < EMBED; k0 += 64) {
        bf16x8 a[2];
        #pragma unroll
        for (int ks = 0; ks < 2; ++ks) {
            float4 h0 = *(const float4*)(hrow + k0 + ks * 32);
            float4 h1 = *(const float4*)(hrow + k0 + ks * 32 + 4);
            bf16x8 tv;
            tv[0] = (__bf16)h0.x; tv[1] = (__bf16)h0.y; tv[2] = (__bf16)h0.z; tv[3] = (__bf16)h0.w;
            tv[4] = (__bf16)h1.x; tv[5] = (__bf16)h1.y; tv[6] = (__bf16)h1.z; tv[7] = (__bf16)h1.w;
            a[ks] = tv;
        }
        #pragma unroll
        for (int j = 0; j < 3; ++j) {
            const int col = w * 48 + j * 16 + lr;       // 0..191
            #pragma unroll
            for (int ks = 0; ks < 2; ++ks) {
                bf16x8 bb = *(const bf16x8*)(wT + (size_t)col * EMBED + k0 + ks * 32 + lg * 8);
                acc[j] = __builtin_amdgcn_mfma_f32_16x16x32_bf16(a[ks], bb, acc[j], 0, 0, 0);
            }
        }
    }

    const float qsc = 0.18033688011112042f;   // log2(e)/sqrt(64)
    const int row0 = m0 + lg * 4;             // C/D: row=(lane>>4)*4+r, col=lr
    #pragma unroll
    for (int j = 0; j < 3; ++j) {
        const int cw  = w * 48 + j * 16;      // 16-col group lies in ONE matrix
        const int mat = cw >> 6;
        const int cm  = (cw & 63) + lr;
        if (mat == 0) {
            const float bb = bq[cm];
            #pragma unroll
            for (int r = 0; r < 4; ++r)
                qo[(size_t)(row0 + r) * HD + cm] = (__bf16)((acc[j][r] + bb) * qsc);
        } else if (mat == 1) {
            const float bb = bk[cm];
            #pragma unroll
            for (int r = 0; r < 4; ++r)
                ko[(size_t)(row0 + r) * HD + cm] = (__bf16)(acc[j][r] + bb);
        } else {
            const float bb = bv[cm];
            bf16x4 pv;
            pv[0] = (__bf16)(acc[j][0] + bb);
            pv[1] = (__bf16)(acc[j][1] + bb);
            pv[2] = (__bf16)(acc[j][2] + bb);
            pv[3] = (__bf16)(acc[j][3] + bb);
            *(bf16x4*)&vto[(size_t)cm * NROW + row0] = pv;   // V transposed
        }
    }
}

// dense partial index helper: bands of 64 rows, 256-key chunks.
// nch(t) = t/4+1; cum(t) = (A+1)*(2A+r), A=t/4, r=t%4.  dense=(cum+c)*4+b.
__device__ __forceinline__ int band_cum(int t) {
    const int A = t >> 2, r = t & 3;
    return (A + 1) * (2 * A + r);
}

// ---------------- causal flash attention, fixed-chunk split-K ----------------
// grid: (MAXCH, 256) x 256 thr (4 waves). y -> band (longest first): t=63-(y>>2),
// b=y&3. x = 256-key chunk; blocks with c >= nch(t) exit. Wave = 16 rows.
// No __syncthreads (per-wave LDS P + lgkmcnt fence).
__global__ __launch_bounds__(256, 8)
void attn_kernel(const __bf16* __restrict__ qg, const __bf16* __restrict__ kg,
                 const __bf16* __restrict__ vtg,
                 float* __restrict__ opart, float* __restrict__ ml) {
    __shared__ __bf16 p_lds[4][16][72];   // per-wave region; 144B stride: 2-way banks

    const int y = blockIdx.y;
    const int t = 63 - (y >> 2);
    const int b = y & 3;
    const int c = blockIdx.x;
    if (c > (t >> 2)) return;             // c >= nch(t)

    const int q0b = t * 64;
    const int kb  = c * 256;

    const int w    = threadIdx.x >> 6;
    const int lane = threadIdx.x & 63, lr = lane & 15, lg = lane >> 4;
    const int q0 = q0b + w * 16;
    const int nk = q0 + 16;
    const int ke = (kb + 256 < nk) ? (kb + 256) : nk;
    if (kb >= ke) return;                 // wave fully beyond its diagonal

    const int dense = (band_cum(t) + c) * 4 + b;
    const int rb = w * 16 + lg * 4;       // row-in-band base

    const __bf16* qb = qg  + (size_t)b * SEQ * HD;
    const __bf16* kp = kg  + (size_t)b * SEQ * HD;
    const __bf16* vb = vtg + (size_t)b * SEQ;   // vb[d*NROW + key]

    const bf16x8 qf0 = *(const bf16x8*)&qb[(q0 + lr) * HD + lg * 8];
    const bf16x8 qf1 = *(const bf16x8*)&qb[(q0 + lr) * HD + 32 + lg * 8];

    f32x4 acc[4];
    const f32x4 zero4 = {0.f, 0.f, 0.f, 0.f};
    #pragma unroll
    for (int n = 0; n < 4; ++n) acc[n] = zero4;
    float m[4], lsum[4];
    #pragma unroll
    for (int r = 0; r < 4; ++r) { m[r] = -INFINITY; lsum[r] = 0.f; }

    for (int kb0 = kb; kb0 < ke; kb0 += 64) {
        f32x4 sj[4];   // scores already in exp2 domain (Q pre-scaled)
        #pragma unroll
        for (int j = 0; j < 4; ++j) {
            bf16x8 kf0 = *(const bf16x8*)&kp[(size_t)(kb0 + j * 16 + lr) * HD + lg * 8];
            bf16x8 kf1 = *(const bf16x8*)&kp[(size_t)(kb0 + j * 16 + lr) * HD + 32 + lg * 8];
            f32x4 z = zero4;
            z = __builtin_amdgcn_mfma_f32_16x16x32_bf16(qf0, kf0, z, 0, 0, 0);
            z = __builtin_amdgcn_mfma_f32_16x16x32_bf16(qf1, kf1, z, 0, 0, 0);
            sj[j] = z;
        }

        if (kb0 + 63 > q0) {  // tile crosses this wave's diagonal: causal mask
            #pragma unroll
            for (int j = 0; j < 4; ++j)
                #pragma unroll
                for (int r = 0; r < 4; ++r)
                    if (kb0 + j * 16 + lr > q0 + lg * 4 + r) sj[j][r] = -1e30f;
        }

        float mx[4];
        #pragma unroll
        for (int r = 0; r < 4; ++r)
            mx[r] = fmaxf(fmaxf(sj[0][r], sj[1][r]), fmaxf(sj[2][r], sj[3][r]));
        #pragma unroll
        for (int off = 1; off < 16; off <<= 1)
            #pragma unroll
            for (int r = 0; r < 4; ++r) mx[r] = fmaxf(mx[r], __shfl_xor(mx[r], off));

        float rs[4], so[4];
        #pragma unroll
        for (int r = 0; r < 4; ++r) {
            const float nm = fmaxf(m[r], mx[r]);
            so[r] = __builtin_exp2f(m[r] - nm);   // m=-inf first iter -> 0
            m[r] = nm;
            float a = 0.f;
            #pragma unroll
            for (int j = 0; j < 4; ++j) {
                sj[j][r] = __builtin_exp2f(sj[j][r] - nm);   // P in place
                a += sj[j][r];
            }
            rs[r] = a;
        }
        #pragma unroll
        for (int off = 1; off < 16; off <<= 1)
            #pragma unroll
            for (int r = 0; r < 4; ++r) rs[r] += __shfl_xor(rs[r], off);
        #pragma unroll
        for (int r = 0; r < 4; ++r) lsum[r] = lsum[r] * so[r] + rs[r];
        #pragma unroll
        for (int n = 0; n < 4; ++n)
            #pragma unroll
            for (int r = 0; r < 4; ++r) acc[n][r] *= so[r];

        // P (16x64) -> per-wave LDS bf16, re-read as A-fragments (fence only)
        #pragma unroll
        for (int j = 0; j < 4; ++j)
            #pragma unroll
            for (int r = 0; r < 4; ++r)
                p_lds[w][lg * 4 + r][j * 16 + lr] = (__bf16)sj[j][r];
        asm volatile("s_waitcnt lgkmcnt(0)" ::: "memory");
        const bf16x8 pa0 = *(const bf16x8*)&p_lds[w][lr][lg * 8];
        const bf16x8 pa1 = *(const bf16x8*)&p_lds[w][lr][32 + lg * 8];
        #pragma unroll
        for (int n = 0; n < 4; ++n) {
            bf16x8 vf0 = *(const bf16x8*)&vb[(size_t)(n * 16 + lr) * NROW + kb0 + lg * 8];
            acc[n] = __builtin_amdgcn_mfma_f32_16x16x32_bf16(pa0, vf0, acc[n], 0, 0, 0);
            bf16x8 vf1 = *(const bf16x8*)&vb[(size_t)(n * 16 + lr) * NROW + kb0 + 32 + lg * 8];
            acc[n] = __builtin_amdgcn_mfma_f32_16x16x32_bf16(pa1, vf1, acc[n], 0, 0, 0);
        }
        asm volatile("" ::: "memory");
    }

    // epilogue: unnormalized O partial + per-row m/l
    float* Op  = opart + (size_t)dense * (64 * 64);
    float* mlp = ml + (size_t)dense * 128;
    #pragma unroll
    for (int n = 0; n < 4; ++n)
        #pragma unroll
        for (int r = 0; r < 4; ++r)
            Op[(size_t)(rb + r) * 64 + n * 16 + lr] = acc[n][r];
    if (lr == 0) {
        #pragma unroll
        for (int r = 0; r < 4; ++r) {
            mlp[rb + r]      = m[r];
            mlp[64 + rb + r] = (m[r] > -1e29f) ? lsum[r] : 0.f;
        }
    }
}

// ---------------- combine split-K partials ----------------
__global__ __launch_bounds__(256)
void reduce_kernel(const float* __restrict__ opart, const float* __restrict__ ml,
                   float* __restrict__ out) {
    const int e   = blockIdx.x * 256 + threadIdx.x;
    const int col = e & 63;
    const int row = e >> 6;                 // global row = b*SEQ + sq
    const int b   = row >> 12;
    const int sq  = row & (SEQ - 1);
    const int t   = sq >> 6;
    const int r64 = sq & 63;
    const int nkr = (sq & ~15) + 16;        // this row's key count
    const int nsp = (nkr + 255) >> 8;       // chunks covering it
    const int cum = band_cum(t);

    float M = -INFINITY, ls = 0.f, o = 0.f;
    for (int sp = 0; sp < nsp; ++sp) {
        const size_t base = (size_t)(cum + sp) * 4 + b;
        const float lv = ml[base * 128 + 64 + r64];
        if (lv > 0.f) {
            const float mv = ml[base * 128 + r64];
            const float nm = fmaxf(M, mv);
            const float f0 = __builtin_exp2f(M - nm);   // M=-inf first -> 0
            const float f1 = __builtin_exp2f(mv - nm);
            const float ov = opart[base * (64 * 64) + (size_t)r64 * 64 + col];
            o  = o * f0 + f1 * ov;
            ls = ls * f0 + f1 * lv;
            M = nm;
        }
    }
    out[e] = o / ls;
}

extern "C" void kernel_launch(void* const* d_in, const int* in_sizes, int n_in,
                              void* d_out, int out_size, void* d_ws, size_t ws_size,
                              hipStream_t stream) {
    const float* hidden = (const float*)d_in[0];
    const float* Wq = (const float*)d_in[1];
    const float* bq = (const float*)d_in[2];
    const float* Wk = (const float*)d_in[3];
    const float* bk = (const float*)d_in[4];
    const float* Wv = (const float*)d_in[5];
    const float* bv = (const float*)d_in[6];

    __bf16* qbuf  = (__bf16*)d_ws;                     // [NROW][64] (pre-scaled)
    __bf16* kbuf  = qbuf + (size_t)NROW * HD;          // [NROW][64]
    __bf16* vtbuf = kbuf + (size_t)NROW * HD;          // [64][NROW] (V transposed)
    __bf16* wT    = vtbuf + (size_t)NROW * HD;         // [192][768]
    float*  opart = (float*)(wT + (size_t)192 * EMBED);        // [NDENSE][64][64]
    float*  ml    = opart + (size_t)NDENSE * 64 * 64;          // [NDENSE][128]

    wconv_kernel<<<(192 * EMBED) / 256, 256, 0, stream>>>(Wq, Wk, Wv, wT);

    qkv_gemm_kernel<<<NROW / 16, 256, 0, stream>>>(
        hidden, wT, bq, bk, bv, qbuf, kbuf, vtbuf);

    attn_kernel<<<dim3(MAXCH, 256), 256, 0, stream>>>(
        qbuf, kbuf, vtbuf, opart, ml);

    reduce_kernel<<<(NROW * HD) / 256, 256, 0, stream>>>(opart, ml, (float*)d_out);
}

// Round 8
// 257.780 us; speedup vs baseline: 1.2949x; 1.2949x over previous
//
#include <hip/hip_runtime.h>
#include <stdint.h>

#define EMBED 768
#define HD 64
#define SEQ 4096
#define BATCH 4
#define NROW (BATCH * SEQ)   // 16384
#define NSTRIP (NROW / 16)   // 1024
#define KSPLIT 4

typedef __bf16 bf16x8 __attribute__((ext_vector_type(8)));
typedef __bf16 bf16x4 __attribute__((ext_vector_type(4)));
typedef float f32x4 __attribute__((ext_vector_type(4)));

// ---------------- W -> wT [192][768] bf16 (once, tiny) ----------------
__global__ __launch_bounds__(256)
void wconv_kernel(const float* __restrict__ Wq, const float* __restrict__ Wk,
                  const float* __restrict__ Wv, __bf16* __restrict__ wT) {
    int id = blockIdx.x * 256 + threadIdx.x;   // < 192*768
    int c = id / EMBED, k = id - c * EMBED;
    const float* W = (c < 64) ? Wq : (c < 128) ? Wk : Wv;
    wT[id] = (__bf16)W[(size_t)k * HD + (c & 63)];
}

// ---------------- fused QKV GEMM ----------------
// grid: 1024 blocks x 256 thr. Block = 16 rows x 192 cols; wave w = 48 cols
// (3 accs). Hidden read 1x (all waves share A rows via L1). A-loads for the
// NEXT k-step are issued before this step's MFMAs (1-deep pipeline).
// Q output PRE-SCALED by log2(e)/sqrt(64) for the attn exp2 softmax.
__global__ __launch_bounds__(256, 4)
void qkv_gemm_kernel(const float* __restrict__ hidden, const __bf16* __restrict__ wT,
                     const float* __restrict__ bq, const float* __restrict__ bk,
                     const float* __restrict__ bv,
                     __bf16* __restrict__ qo, __bf16* __restrict__ ko,
                     __bf16* __restrict__ vto) {
    const int m0 = blockIdx.x * 16;
    const int w  = threadIdx.x >> 6;
    const int lane = threadIdx.x & 63, lr = lane & 15, lg = lane >> 4;

    f32x4 acc[3];
    #pragma unroll
    for (int j = 0; j < 3; ++j) acc[j] = (f32x4){0.f, 0.f, 0.f, 0.f};

    const float* hrow = hidden + (size_t)(m0 + lr) * EMBED + lg * 8;

    float4 c00 = *(const float4*)(hrow + 0);
    float4 c01 = *(const float4*)(hrow + 4);
    float4 c10 = *(const float4*)(hrow + 32);
    float4 c11 = *(const float4*)(hrow + 36);

    for (int k0 = 0; k0 < EMBED; k0 += 64) {
        // prefetch next k-step's A (clamped addr on last iter: harmless reload)
        const float* pf = hrow + ((k0 + 64 < EMBED) ? (k0 + 64) : k0);
        float4 n00 = *(const float4*)(pf + 0);
        float4 n01 = *(const float4*)(pf + 4);
        float4 n10 = *(const float4*)(pf + 32);
        float4 n11 = *(const float4*)(pf + 36);

        bf16x8 a0, a1;
        a0[0] = (__bf16)c00.x; a0[1] = (__bf16)c00.y; a0[2] = (__bf16)c00.z; a0[3] = (__bf16)c00.w;
        a0[4] = (__bf16)c01.x; a0[5] = (__bf16)c01.y; a0[6] = (__bf16)c01.z; a0[7] = (__bf16)c01.w;
        a1[0] = (__bf16)c10.x; a1[1] = (__bf16)c10.y; a1[2] = (__bf16)c10.z; a1[3] = (__bf16)c10.w;
        a1[4] = (__bf16)c11.x; a1[5] = (__bf16)c11.y; a1[6] = (__bf16)c11.z; a1[7] = (__bf16)c11.w;

        #pragma unroll
        for (int j = 0; j < 3; ++j) {
            const int col = w * 48 + j * 16 + lr;       // 0..191
            bf16x8 b0 = *(const bf16x8*)(wT + (size_t)col * EMBED + k0 + lg * 8);
            acc[j] = __builtin_amdgcn_mfma_f32_16x16x32_bf16(a0, b0, acc[j], 0, 0, 0);
            bf16x8 b1 = *(const bf16x8*)(wT + (size_t)col * EMBED + k0 + 32 + lg * 8);
            acc[j] = __builtin_amdgcn_mfma_f32_16x16x32_bf16(a1, b1, acc[j], 0, 0, 0);
        }
        c00 = n00; c01 = n01; c10 = n10; c11 = n11;
    }

    const float qsc = 0.18033688011112042f;   // log2(e)/sqrt(64)
    const int row0 = m0 + lg * 4;             // C/D: row=(lane>>4)*4+r, col=lr
    #pragma unroll
    for (int j = 0; j < 3; ++j) {
        const int cw  = w * 48 + j * 16;      // 16-col group lies in ONE matrix
        const int mat = cw >> 6;
        const int cm  = (cw & 63) + lr;
        if (mat == 0) {
            const float bb = bq[cm];
            #pragma unroll
            for (int r = 0; r < 4; ++r)
                qo[(size_t)(row0 + r) * HD + cm] = (__bf16)((acc[j][r] + bb) * qsc);
        } else if (mat == 1) {
            const float bb = bk[cm];
            #pragma unroll
            for (int r = 0; r < 4; ++r)
                ko[(size_t)(row0 + r) * HD + cm] = (__bf16)(acc[j][r] + bb);
        } else {
            const float bb = bv[cm];
            bf16x4 pv;
            pv[0] = (__bf16)(acc[j][0] + bb);
            pv[1] = (__bf16)(acc[j][1] + bb);
            pv[2] = (__bf16)(acc[j][2] + bb);
            pv[3] = (__bf16)(acc[j][3] + bb);
            *(bf16x4*)&vto[(size_t)cm * NROW + row0] = pv;   // V transposed
        }
    }
}

// ---------------- causal flash attention ----------------
// grid: NSTRIP*KSPLIT = 4096 blocks x 128 thr (2 waves). Block = one 16-row
// strip x one key chunk; the 2 waves split the chunk's keys and flash-merge
// in LDS at the end (one __syncthreads). Longest strips dispatched first.
// Partials: [NSTRIP][KSPLIT][16][64] f32 + (m,l) — 16.8 MB total.
__global__ __launch_bounds__(128, 8)
void attn_kernel(const __bf16* __restrict__ qg, const __bf16* __restrict__ kg,
                 const __bf16* __restrict__ vtg,
                 float* __restrict__ opart, float* __restrict__ ml) {
    __shared__ __bf16 p_lds[2][16][72];    // per-wave P; 144B stride: 2-way banks
    __shared__ float  macc[16][64];        // wave1 -> wave0 merge buffer
    __shared__ float  mml[32];

    const int bid   = blockIdx.x;
    const int s     = (NSTRIP - 1) - (bid >> 2);   // descending work
    const int split = bid & 3;
    const int b     = s & 3;
    const int q0    = (s >> 2) * 16;
    const int w     = threadIdx.x >> 6;
    const int lane  = threadIdx.x & 63, lr = lane & 15, lg = lane >> 4;

    const int nk    = q0 + 16;
    const int chunk = ((nk + KSPLIT * 64 - 1) / (KSPLIT * 64)) * 64;
    const int kb    = split * chunk;
    const int ke    = (kb + chunk < nk) ? (kb + chunk) : nk;

    // this wave's key sub-range (64-aligned halves of the chunk's tiles)
    const int nblk = (ke > kb) ? ((ke - kb + 63) >> 6) : 0;
    const int hblk = (nblk + 1) >> 1;
    const int wkb  = kb + w * hblk * 64;
    const int wke0 = wkb + hblk * 64;
    const int wke  = (wke0 < ke) ? wke0 : ke;

    const __bf16* qb = qg  + (size_t)b * SEQ * HD;
    const __bf16* kp = kg  + (size_t)b * SEQ * HD;
    const __bf16* vb = vtg + (size_t)b * SEQ;   // vb[d*NROW + key]

    const bf16x8 qf0 = *(const bf16x8*)&qb[(q0 + lr) * HD + lg * 8];
    const bf16x8 qf1 = *(const bf16x8*)&qb[(q0 + lr) * HD + 32 + lg * 8];

    f32x4 acc[4];
    const f32x4 zero4 = {0.f, 0.f, 0.f, 0.f};
    #pragma unroll
    for (int n = 0; n < 4; ++n) acc[n] = zero4;
    float m[4], lsum[4];
    #pragma unroll
    for (int r = 0; r < 4; ++r) { m[r] = -INFINITY; lsum[r] = 0.f; }

    for (int kb0 = wkb; kb0 < wke; kb0 += 64) {
        f32x4 sj[4];   // scores already in exp2 domain (Q pre-scaled)
        #pragma unroll
        for (int j = 0; j < 4; ++j) {
            bf16x8 kf0 = *(const bf16x8*)&kp[(size_t)(kb0 + j * 16 + lr) * HD + lg * 8];
            bf16x8 kf1 = *(const bf16x8*)&kp[(size_t)(kb0 + j * 16 + lr) * HD + 32 + lg * 8];
            f32x4 z = zero4;
            z = __builtin_amdgcn_mfma_f32_16x16x32_bf16(qf0, kf0, z, 0, 0, 0);
            z = __builtin_amdgcn_mfma_f32_16x16x32_bf16(qf1, kf1, z, 0, 0, 0);
            sj[j] = z;
        }

        if (kb0 + 63 > q0) {  // tile crosses this strip's diagonal: causal mask
            #pragma unroll
            for (int j = 0; j < 4; ++j)
                #pragma unroll
                for (int r = 0; r < 4; ++r)
                    if (kb0 + j * 16 + lr > q0 + lg * 4 + r) sj[j][r] = -1e30f;
        }

        float mx[4];
        #pragma unroll
        for (int r = 0; r < 4; ++r)
            mx[r] = fmaxf(fmaxf(sj[0][r], sj[1][r]), fmaxf(sj[2][r], sj[3][r]));
        #pragma unroll
        for (int off = 1; off < 16; off <<= 1)
            #pragma unroll
            for (int r = 0; r < 4; ++r) mx[r] = fmaxf(mx[r], __shfl_xor(mx[r], off));

        float rs[4], so[4];
        #pragma unroll
        for (int r = 0; r < 4; ++r) {
            const float nm = fmaxf(m[r], mx[r]);
            so[r] = __builtin_exp2f(m[r] - nm);   // m=-inf first iter -> 0
            m[r] = nm;
            float a = 0.f;
            #pragma unroll
            for (int j = 0; j < 4; ++j) {
                sj[j][r] = __builtin_exp2f(sj[j][r] - nm);   // P in place
                a += sj[j][r];
            }
            rs[r] = a;
        }
        #pragma unroll
        for (int off = 1; off < 16; off <<= 1)
            #pragma unroll
            for (int r = 0; r < 4; ++r) rs[r] += __shfl_xor(rs[r], off);
        #pragma unroll
        for (int r = 0; r < 4; ++r) lsum[r] = lsum[r] * so[r] + rs[r];
        #pragma unroll
        for (int n = 0; n < 4; ++n)
            #pragma unroll
            for (int r = 0; r < 4; ++r) acc[n][r] *= so[r];

        // P (16x64) -> per-wave LDS bf16, re-read as A-fragments (fence only)
        #pragma unroll
        for (int j = 0; j < 4; ++j)
            #pragma unroll
            for (int r = 0; r < 4; ++r)
                p_lds[w][lg * 4 + r][j * 16 + lr] = (__bf16)sj[j][r];
        asm volatile("s_waitcnt lgkmcnt(0)" ::: "memory");
        const bf16x8 pa0 = *(const bf16x8*)&p_lds[w][lr][lg * 8];
        const bf16x8 pa1 = *(const bf16x8*)&p_lds[w][lr][32 + lg * 8];
        #pragma unroll
        for (int n = 0; n < 4; ++n) {
            bf16x8 vf0 = *(const bf16x8*)&vb[(size_t)(n * 16 + lr) * NROW + kb0 + lg * 8];
            acc[n] = __builtin_amdgcn_mfma_f32_16x16x32_bf16(pa0, vf0, acc[n], 0, 0, 0);
            bf16x8 vf1 = *(const bf16x8*)&vb[(size_t)(n * 16 + lr) * NROW + kb0 + 32 + lg * 8];
            acc[n] = __builtin_amdgcn_mfma_f32_16x16x32_bf16(pa1, vf1, acc[n], 0, 0, 0);
        }
        asm volatile("" ::: "memory");
    }

    const int rb = lg * 4;   // thread's 4 strip-local rows: rb..rb+3

    // ---- 2-wave flash merge in LDS (both waves reach the barrier) ----
    if (w == 1) {
        #pragma unroll
        for (int n = 0; n < 4; ++n)
            #pragma unroll
            for (int r = 0; r < 4; ++r)
                macc[rb + r][n * 16 + lr] = acc[n][r];
        if (lr == 0) {
            #pragma unroll
            for (int r = 0; r < 4; ++r) {
                mml[rb + r]      = m[r];
                mml[16 + rb + r] = (m[r] > -1e29f) ? lsum[r] : 0.f;
            }
        }
    }
    __syncthreads();
    if (w == 0) {
        float* Op  = opart + ((size_t)s * KSPLIT + split) * (16 * 64);
        float* mlp = ml + ((size_t)s * KSPLIT + split) * 32;
        float l0g[4], f0[4], f1[4], nmv[4], l1[4];
        #pragma unroll
        for (int r = 0; r < 4; ++r) {
            const float m1 = mml[rb + r];
            l1[r] = mml[16 + rb + r];
            l0g[r] = (m[r] > -1e29f) ? lsum[r] : 0.f;
            const float nm = fmaxf(m[r], m1);
            f0[r] = (m[r] > -1e29f) ? __builtin_exp2f(m[r] - nm) : 0.f;
            f1[r] = (m1   > -1e29f) ? __builtin_exp2f(m1   - nm) : 0.f;
            nmv[r] = nm;
        }
        #pragma unroll
        for (int n = 0; n < 4; ++n)
            #pragma unroll
            for (int r = 0; r < 4; ++r)
                Op[(size_t)(rb + r) * 64 + n * 16 + lr] =
                    acc[n][r] * f0[r] + macc[rb + r][n * 16 + lr] * f1[r];
        if (lr == 0) {
            #pragma unroll
            for (int r = 0; r < 4; ++r) {
                mlp[rb + r]      = nmv[r];
                mlp[16 + rb + r] = l0g[r] * f0[r] + l1[r] * f1[r];
            }
        }
    }
}

// ---------------- combine split-K partials ----------------
// grid: NROW*HD/256 x 256 thr; one thread per output element.
__global__ __launch_bounds__(256)
void reduce_kernel(const float* __restrict__ opart, const float* __restrict__ ml,
                   float* __restrict__ out) {
    const int e   = blockIdx.x * 256 + threadIdx.x;
    const int col = e & 63;
    const int row = e >> 6;                 // global row = b*SEQ + sq
    const int b   = row >> 12;
    const int sq  = row & (SEQ - 1);
    const int s   = ((sq >> 4) << 2) | b;
    const int r   = sq & 15;
    const int nk  = (sq & ~15) + 16;
    const int chunk = ((nk + KSPLIT * 64 - 1) / (KSPLIT * 64)) * 64;
    const int nsp   = (nk + chunk - 1) / chunk;

    float M = -INFINITY, ls = 0.f, o = 0.f;
    for (int sp = 0; sp < nsp; ++sp) {
        const float* mlp = ml + ((size_t)s * KSPLIT + sp) * 32;
        const float lv = mlp[16 + r];
        if (lv > 0.f) {
            const float mv = mlp[r];
            const float nm = fmaxf(M, mv);
            const float f0 = __builtin_exp2f(M - nm);   // M=-inf first -> 0
            const float f1 = __builtin_exp2f(mv - nm);
            const float ov = opart[((size_t)s * KSPLIT + sp) * (16 * 64) + (size_t)r * 64 + col];
            o  = o * f0 + f1 * ov;
            ls = ls * f0 + f1 * lv;
            M = nm;
        }
    }
    out[e] = o / ls;
}

extern "C" void kernel_launch(void* const* d_in, const int* in_sizes, int n_in,
                              void* d_out, int out_size, void* d_ws, size_t ws_size,
                              hipStream_t stream) {
    const float* hidden = (const float*)d_in[0];
    const float* Wq = (const float*)d_in[1];
    const float* bq = (const float*)d_in[2];
    const float* Wk = (const float*)d_in[3];
    const float* bk = (const float*)d_in[4];
    const float* Wv = (const float*)d_in[5];
    const float* bv = (const float*)d_in[6];

    __bf16* qbuf  = (__bf16*)d_ws;                     // [NROW][64] (pre-scaled)
    __bf16* kbuf  = qbuf + (size_t)NROW * HD;          // [NROW][64]
    __bf16* vtbuf = kbuf + (size_t)NROW * HD;          // [64][NROW] (V transposed)
    __bf16* wT    = vtbuf + (size_t)NROW * HD;         // [192][768]
    float*  opart = (float*)(wT + (size_t)192 * EMBED);            // [NSTRIP][KSPLIT][16][64]
    float*  ml    = opart + (size_t)NSTRIP * KSPLIT * 16 * 64;     // [NSTRIP][KSPLIT][32]

    wconv_kernel<<<(192 * EMBED) / 256, 256, 0, stream>>>(Wq, Wk, Wv, wT);

    qkv_gemm_kernel<<<NROW / 16, 256, 0, stream>>>(
        hidden, wT, bq, bk, bv, qbuf, kbuf, vtbuf);

    attn_kernel<<<NSTRIP * KSPLIT, 128, 0, stream>>>(
        qbuf, kbuf, vtbuf, opart, ml);

    reduce_kernel<<<(NROW * HD) / 256, 256, 0, stream>>>(opart, ml, (float*)d_out);
}